// Round 11
// baseline (910.868 us; speedup 1.0000x reference)
//
#include <hip/hip_runtime.h>
#include <math.h>

#define NN 20000
#define NE 320000
#define AVG_LOG_F 2.83321334f

typedef unsigned short u16;
typedef _Float16 h8_t __attribute__((ext_vector_type(8)));
typedef float f4_t __attribute__((ext_vector_type(4)));

__device__ __forceinline__ u16 f2h(float f) {
  _Float16 h = (_Float16)f;
  return __builtin_bit_cast(u16, h);
}
__device__ __forceinline__ void gld16(const void* g, void* l) {
  __builtin_amdgcn_global_load_lds(
      (const __attribute__((address_space(1))) void*)g,
      (__attribute__((address_space(3))) void*)l, 16, 0, 0);
}

// ---------------- CSR build (both channels in one pass) ----------------
__global__ __launch_bounds__(256) void k_count2(const int* __restrict__ ein,
                                                const int* __restrict__ eout,
                                                int* __restrict__ deg2, int E) {
  int e = blockIdx.x * 256 + threadIdx.x;
  int ch = blockIdx.y;
  const int* dst = (ch ? eout : ein) + E;
  if (e < E) atomicAdd(&deg2[ch * NN + dst[e]], 1);
}

__global__ __launch_bounds__(1024) void k_scan(const int* __restrict__ deg,
                                               int* __restrict__ rp, int N) {
  __shared__ int lds[1024];
  int t = threadIdx.x;
  int CH = (N + 1023) >> 10;
  int base = t * CH;
  int s = 0;
  for (int i = 0; i < CH; ++i) { int idx = base + i; if (idx < N) s += deg[idx]; }
  lds[t] = s;
  __syncthreads();
  for (int off = 1; off < 1024; off <<= 1) {
    int v = (t >= off) ? lds[t - off] : 0;
    __syncthreads();
    lds[t] += v;
    __syncthreads();
  }
  int run = (t == 0) ? 0 : lds[t - 1];
  for (int i = 0; i < CH; ++i) {
    int idx = base + i;
    if (idx < N) { rp[idx] = run; run += deg[idx]; }
  }
  if (t == 1023) rp[N] = run;
}

__global__ __launch_bounds__(256) void k_scatter2(const int* __restrict__ ein,
                                                  const int* __restrict__ eout,
                                                  const int* __restrict__ rp2,
                                                  int* __restrict__ cur2,
                                                  int* __restrict__ col2, int E) {
  int e = blockIdx.x * 256 + threadIdx.x;
  int ch = blockIdx.y;
  const int* src = (ch ? eout : ein);
  const int* dst = src + E;
  if (e < E) {
    int d = dst[e];
    int p = atomicAdd(&cur2[ch * NN + d], 1);
    col2[rp2[ch * NN + d] + p] = src[e];
  }
}

// ---------------- converts ----------------
// merged weight convert. pre2 layout: [(lyr*2+ch)][256][512] fp16.
__global__ __launch_bounds__(256) void k_cvtw(
    const float* __restrict__ Wpre_s, const float* __restrict__ Wpre_d,
    const float* __restrict__ Wlin_s, const float* __restrict__ Wlin_d,
    const float* __restrict__ Wcomb,
    u16* __restrict__ pre2, u16* __restrict__ lincat, u16* __restrict__ combB) {
  int i = blockIdx.x * 256 + threadIdx.x;  // float4 index
  const float* src;
  u16* dst;
  int so, dofs;
  if (i < 65536)       { int j = i; int lyr = j >> 15;
                         src = Wpre_s; dst = pre2; so = j;
                         dofs = (lyr * 2 + 0) * 32768 + (j & 32767); }
  else if (i < 131072) { int j = i - 65536; int lyr = j >> 15;
                         src = Wpre_d; dst = pre2; so = j;
                         dofs = (lyr * 2 + 1) * 32768 + (j & 32767); }
  else if (i < 163840) { int j = i - 131072; int lyr = j >> 14;
                         src = Wlin_s; dst = lincat; so = j; dofs = j + lyr * 16384; }
  else if (i < 196608) { int j = i - 163840; int lyr = j >> 14;
                         src = Wlin_d; dst = lincat; so = j; dofs = j + (lyr + 1) * 16384; }
  else if (i < 294912) { src = Wcomb; dst = combB; so = i - 196608; dofs = so; }
  else return;
  float4 v = *(const float4*)(src + (size_t)so * 4);
  ushort4 o;
  o.x = f2h(v.x); o.y = f2h(v.y); o.z = f2h(v.z); o.w = f2h(v.w);
  *(ushort4*)(dst + (size_t)dofs * 4) = o;
}

// x0 -> xcat1[:,0:256] (ld 768); also bpre4 concat (tiny, first blocks)
__global__ __launch_bounds__(256) void k_cvtx(const float* __restrict__ x,
                                              u16* __restrict__ xc,
                                              const float* __restrict__ bpre_s,
                                              const float* __restrict__ bpre_d,
                                              float* __restrict__ bpre4) {
  int i = blockIdx.x * 256 + threadIdx.x;  // over NN*64
  int row = i >> 6, c = (i & 63) * 4;
  float4 v = *(const float4*)(x + (size_t)row * 256 + c);
  ushort4 o;
  o.x = f2h(v.x); o.y = f2h(v.y); o.z = f2h(v.z); o.w = f2h(v.w);
  *(ushort4*)(xc + (size_t)row * 768 + c) = o;
  if (i < 1024) {
    // bpre4[(lyr*2+ch)*256 + n]
    int z = i >> 8, n = i & 255;
    int lyr = z >> 1, ch = z & 1;
    bpre4[i] = (ch ? bpre_d : bpre_s)[lyr * 256 + n];
  }
}

// transpose-convert Wpost [256,4096] f32 -> [4096,256] fp16, all 4 (lyr,ch)
__global__ __launch_bounds__(256) void k_tc4(const float* __restrict__ Ws,
                                             const float* __restrict__ Wd,
                                             u16* __restrict__ outT) {
  __shared__ float tile[32][33];
  int z = blockIdx.z;
  const float* in = ((z & 1) ? Wd : Ws) + (size_t)(z >> 1) * 256 * 4096;
  u16* out = outT + (size_t)z * (4096 * 256);
  int bx = blockIdx.x, by = blockIdx.y;
  int r = threadIdx.x >> 5, c = threadIdx.x & 31;
#pragma unroll
  for (int it = 0; it < 4; ++it)
    tile[r + it * 8][c] = in[(size_t)(by * 32 + r + it * 8) * 4096 + bx * 32 + c];
  __syncthreads();
#pragma unroll
  for (int it = 0; it < 4; ++it)
    out[(size_t)(bx * 32 + r + it * 8) * 256 + by * 32 + c] = f2h(tile[c][r + it * 8]);
}

// ---------------- MFMA fp16 GEMM, double-buffered (pre/Wf/comb) ----------------
// bias indexed with z stride zBias.
__global__ __launch_bounds__(512) void k_mgemm(
    const u16* __restrict__ A, int lda,
    const u16* __restrict__ B, const u16* __restrict__ B2, int ldb, int nsplit,
    const float* __restrict__ bias, int zBias,
    u16* __restrict__ oH, int ldoH,
    int M, int K, int relu, int zA, int zB, int zO) {
  __shared__ u16 As[2][64 * 64];
  __shared__ u16 Bs[2][256 * 64];
  const int t = threadIdx.x;
  const int z = blockIdx.z;
  A += (size_t)z * zA;
  B += (size_t)z * zB;
  B2 += (size_t)z * zB;
  oH += (size_t)z * zO;
  if (bias) bias += (size_t)z * zBias;
  const int m0 = blockIdx.y * 64;
  const int n0 = blockIdx.x * 256;
  const int l = t & 63, w = t >> 6;
  const int wm = w >> 2, wn = w & 3;
  const int lo = l & 15, hi = l >> 4;

  f4_t acc[2][4];
#pragma unroll
  for (int i = 0; i < 2; ++i)
#pragma unroll
    for (int j = 0; j < 4; ++j) acc[i][j] = (f4_t)0.f;

  const int ra = t >> 3, pa = t & 7;
  const int la = pa ^ (ra & 7);
  int rra = m0 + ra;
  if (rra > M - 1) rra = M - 1;
  const u16* gA = A + (size_t)rra * lda + la * 8;

  const u16* gB[4];
  int lBo[4];
#pragma unroll
  for (int i = 0; i < 4; ++i) {
    int q = i * 512 + t;
    int r = q >> 3, p2 = q & 7;
    int lc = p2 ^ (r & 7);
    int n = n0 + r;
    const u16* bp = (n < nsplit) ? (B + (size_t)n * ldb) : (B2 + (size_t)(n - nsplit) * ldb);
    gB[i] = bp + lc * 8;
    lBo[i] = q * 8;
  }

  gld16(gA, &As[0][t * 8]);
#pragma unroll
  for (int i = 0; i < 4; ++i) gld16(gB[i], &Bs[0][lBo[i]]);
  __syncthreads();

  const int nt = K >> 6;
  for (int tt = 0; tt < nt; ++tt) {
    const int cur = tt & 1;
    if (tt + 1 < nt) {
      const int ko = (tt + 1) << 6;
      gld16(gA + ko, &As[cur ^ 1][t * 8]);
#pragma unroll
      for (int i = 0; i < 4; ++i) gld16(gB[i] + ko, &Bs[cur ^ 1][lBo[i]]);
    }
#pragma unroll
    for (int ks = 0; ks < 2; ++ks) {
      h8_t af[2], bfr[4];
#pragma unroll
      for (int mi = 0; mi < 2; ++mi) {
        int row = wm * 32 + mi * 16 + lo;
        int c = (ks * 4 + hi) ^ (row & 7);
        af[mi] = *(const h8_t*)&As[cur][row * 64 + c * 8];
      }
#pragma unroll
      for (int ni = 0; ni < 4; ++ni) {
        int row = wn * 64 + ni * 16 + lo;
        int c = (ks * 4 + hi) ^ (row & 7);
        bfr[ni] = *(const h8_t*)&Bs[cur][row * 64 + c * 8];
      }
#pragma unroll
      for (int mi = 0; mi < 2; ++mi)
#pragma unroll
        for (int ni = 0; ni < 4; ++ni)
          acc[mi][ni] = __builtin_amdgcn_mfma_f32_16x16x32_f16(
              af[mi], bfr[ni], acc[mi][ni], 0, 0, 0);
    }
    __syncthreads();
  }

  float bv[4];
#pragma unroll
  for (int ni = 0; ni < 4; ++ni) {
    int n = n0 + wn * 64 + ni * 16 + lo;
    bv[ni] = (n < nsplit) ? (bias ? bias[n] : 0.f) : 0.f;
  }
#pragma unroll
  for (int mi = 0; mi < 2; ++mi) {
#pragma unroll
    for (int r = 0; r < 4; ++r) {
      int m = m0 + wm * 32 + mi * 16 + hi * 4 + r;
      if (m < M) {
#pragma unroll
        for (int ni = 0; ni < 4; ++ni) {
          int n = n0 + wn * 64 + ni * 16 + lo;
          float v = acc[mi][ni][r] + bv[ni];
          if (relu && v < 0.f) v = 0.f;
          oH[(size_t)m * ldoH + n] = f2h(v);
        }
      }
    }
  }
}

// ---------------- post GEMM: BM=128 x BN=256, XCD-channel-partitioned grid ----------------
// virtual A = [x | agg | agg*s1 | agg*s2] (K=4096); B = Wf[ch]; out fp16 into xc cols.
// Flat grid 320: xcd = wg&7; XCDs 0-3 -> ch0, 4-7 -> ch1 (per-XCD Wf = 2MB, L2-resident).
// Inner loop = proven round-2/10 structure; A staging extended to 2 rows/thread.
__global__ __launch_bounds__(512) void k_pgemm(
    const u16* __restrict__ xc, const u16* __restrict__ agg5c,
    const float* __restrict__ scal3c, const u16* __restrict__ Wfl,
    const float* __restrict__ bfl, u16* __restrict__ oHb, int M) {
  __shared__ u16 As[128 * 64];
  __shared__ u16 Bs[256 * 64];
  const int t = threadIdx.x;
  const int wg = blockIdx.x;
  const int xcd = wg & 7;
  const int ch = xcd >> 2;
  const int mt = (wg >> 3) * 4 + (xcd & 3);
  if (mt >= 157) return;
  const int m0 = mt * 128;
  const u16* agg5 = agg5c + (size_t)ch * NN * 1280;
  const float* scal3 = scal3c + (size_t)ch * NN * 4;
  const u16* Wf = Wfl + (size_t)ch * (256 * 4096);
  const float* bf = bfl + ch * 256;
  u16* oH = oHb + 256 + ch * 256;  // ldoH = 768
  const int l = t & 63, w = t >> 6;
  const int wm = w >> 2, wn = w & 3;   // wm in {0,1}: 64-row half; wn in [0,4): 64-col quarter
  const int lo = l & 15, hi = l >> 4;

  f4_t acc[4][4];
#pragma unroll
  for (int i = 0; i < 4; ++i)
#pragma unroll
    for (int j = 0; j < 4; ++j) acc[i][j] = (f4_t)0.f;

  // A reg-staging: thread -> rows ra and ra+64, k-chunk pa (8 fp16 each); swizzled slots.
  // (ra+64)&7 == ra&7, so slot1 = slot0 + 64*64.
  const int ra = t >> 3, pa = t & 7;
  int mr0 = m0 + ra;
  if (mr0 > M - 1) mr0 = M - 1;
  int mr1 = m0 + ra + 64;
  if (mr1 > M - 1) mr1 = M - 1;
  u16* ldA0 = &As[ra * 64 + (pa ^ (ra & 7)) * 8];
  u16* ldA1 = ldA0 + 64 * 64;
  const u16* xrow0 = xc + (size_t)mr0 * 768;
  const u16* xrow1 = xc + (size_t)mr1 * 768;
  const u16* arow0 = agg5 + (size_t)mr0 * 1280;
  const u16* arow1 = agg5 + (size_t)mr1 * 1280;
  const float* srow0 = scal3 + (size_t)mr0 * 4;
  const float* srow1 = scal3 + (size_t)mr1 * 4;

  // B: direct global->LDS, pre-swizzled source (full Nout=256), byte-identical to proven.
  const u16* gB[4];
  u16* lB[4];
#pragma unroll
  for (int i = 0; i < 4; ++i) {
    int q = i * 512 + t;
    int r = q >> 3, p2 = q & 7;
    int lc = p2 ^ (r & 7);
    gB[i] = Wf + (size_t)r * 4096 + lc * 8;
    lB[i] = &Bs[q * 8];
  }

  for (int k0 = 0; k0 < 4096; k0 += 64) {
#pragma unroll
    for (int i = 0; i < 4; ++i) gld16(gB[i] + k0, lB[i]);
    int k = k0 + pa * 8;
    h8_t v0, v1;
    if (k < 256) {
      v0 = *(const h8_t*)(xrow0 + k);
      v1 = *(const h8_t*)(xrow1 + k);
    } else {
      int q = k - 256;
      int g = q / 1280;
      int r2 = q - g * 1280;
      v0 = *(const h8_t*)(arow0 + r2);
      v1 = *(const h8_t*)(arow1 + r2);
      v0 = v0 * (_Float16)srow0[g];
      v1 = v1 * (_Float16)srow1[g];
    }
    *(h8_t*)ldA0 = v0;
    *(h8_t*)ldA1 = v1;
    __syncthreads();
#pragma unroll
    for (int ks = 0; ks < 2; ++ks) {
      h8_t af[4], bfr[4];
#pragma unroll
      for (int mi = 0; mi < 4; ++mi) {
        int row = wm * 64 + mi * 16 + lo;
        int c = (ks * 4 + hi) ^ (row & 7);
        af[mi] = *(const h8_t*)&As[row * 64 + c * 8];
      }
#pragma unroll
      for (int ni = 0; ni < 4; ++ni) {
        int row = wn * 64 + ni * 16 + lo;
        int c = (ks * 4 + hi) ^ (row & 7);
        bfr[ni] = *(const h8_t*)&Bs[row * 64 + c * 8];
      }
#pragma unroll
      for (int mi = 0; mi < 4; ++mi)
#pragma unroll
        for (int ni = 0; ni < 4; ++ni)
          acc[mi][ni] = __builtin_amdgcn_mfma_f32_16x16x32_f16(
              af[mi], bfr[ni], acc[mi][ni], 0, 0, 0);
    }
    __syncthreads();
  }

  float bv[4];
#pragma unroll
  for (int ni = 0; ni < 4; ++ni) bv[ni] = bf[wn * 64 + ni * 16 + lo];
#pragma unroll
  for (int mi = 0; mi < 4; ++mi) {
#pragma unroll
    for (int r = 0; r < 4; ++r) {
      int mr = m0 + wm * 64 + mi * 16 + hi * 4 + r;
      if (mr < M) {
#pragma unroll
        for (int ni = 0; ni < 4; ++ni) {
          int n = wn * 64 + ni * 16 + lo;
          float vv = acc[mi][ni][r] + bv[ni];
          if (vv < 0.f) vv = 0.f;
          oH[(size_t)mr * 768 + n] = f2h(vv);
        }
      }
    }
  }
}

// ---------------- aggregation: both channels, wave/node, 16B loads ----------------
__global__ __launch_bounds__(256) void k_aggregate(
    const u16* __restrict__ AB2, const int* __restrict__ rp2,
    const int* __restrict__ col2, u16* __restrict__ agg52,
    float* __restrict__ scal32) {
  int ch = blockIdx.y;
  const u16* AB = AB2 + (size_t)ch * NN * 512;
  const int* rp = rp2 + ch * NN;
  u16* agg5 = agg52 + (size_t)ch * NN * 1280;
  float* scal3 = scal32 + (size_t)ch * NN * 4;
  int w = threadIdx.x >> 6, l = threadIdx.x & 63;
  int n = blockIdx.x * 4 + w;
  int beg = rp[n], end = rp[n + 1];
  int deg = end - beg;
  int half = l >> 5, lf = l & 31;
  float sb[8], qb[8], mnb[8], mxb[8];
#pragma unroll
  for (int j = 0; j < 8; ++j) {
    sb[j] = 0.f; qb[j] = 0.f;
    mnb[j] = 3.402823466e38f; mxb[j] = -3.402823466e38f;
  }
  for (int i = beg + half; i < end; i += 2) {
    int s = col2[i];
    h8_t bv = *(const h8_t*)(AB + (size_t)s * 512 + 256 + lf * 8);
#pragma unroll
    for (int j = 0; j < 8; ++j) {
      float b = (float)bv[j];
      sb[j] += b;
      qb[j] = fmaf(b, b, qb[j]);
      mnb[j] = fminf(mnb[j], b);
      mxb[j] = fmaxf(mxb[j], b);
    }
  }
#pragma unroll
  for (int j = 0; j < 8; ++j) {
    sb[j] += __shfl_xor(sb[j], 32, 64);
    qb[j] += __shfl_xor(qb[j], 32, 64);
    mnb[j] = fminf(mnb[j], __shfl_xor(mnb[j], 32, 64));
    mxb[j] = fmaxf(mxb[j], __shfl_xor(mxb[j], 32, 64));
  }
  h8_t cv = *(const h8_t*)(AB + (size_t)n * 512 + lf * 8);
  float degf = (float)deg;
  float degc = degf > 1.f ? degf : 1.f;
  float inv = 1.f / degc;
  float ov[5][8];
#pragma unroll
  for (int j = 0; j < 8; ++j) {
    float c = (float)cv[j];
    float s_m = fmaf(degf, c, sb[j]);
    float mean = s_m * inv;
    float mean2 = fmaf(degf * c, c, fmaf(2.f * c, sb[j], qb[j])) * inv;
    float var = mean2 - mean * mean;
    if (var < 0.f) var = 0.f;
    float sd = sqrtf(var + 1e-5f);
    ov[0][j] = mean;
    ov[1][j] = s_m;
    ov[2][j] = sd;
    ov[3][j] = deg > 0 ? c + mnb[j] : 0.f;
    ov[4][j] = deg > 0 ? c + mxb[j] : 0.f;
  }
  if (half == 0) {
    u16* base = agg5 + (size_t)n * 1280 + lf * 8;
#pragma unroll
    for (int a = 0; a < 5; ++a) {
      h8_t o;
#pragma unroll
      for (int j = 0; j < 8; ++j) o[j] = (_Float16)ov[a][j];
      *(h8_t*)(base + a * 256) = o;
    }
    if (lf == 0) {
      float logd = logf(degc + 1.f);
      float4 sc = make_float4(1.f, logd / AVG_LOG_F, AVG_LOG_F / logd, 0.f);
      *(float4*)(scal3 + (size_t)n * 4) = sc;
    }
  }
}

// bf = Wlin @ bpost + blin (fp32), all 4 (lyr,ch)
__global__ __launch_bounds__(256) void k_bfuse4(
    const float* __restrict__ Wlin_s, const float* __restrict__ Wlin_d,
    const float* __restrict__ bpost_s, const float* __restrict__ bpost_d,
    const float* __restrict__ blin_s, const float* __restrict__ blin_d,
    float* __restrict__ bfv4) {
  __shared__ float bp[256];
  int z = blockIdx.x, lyr = z >> 1, ch = z & 1;
  const float* Wlin = (ch ? Wlin_d : Wlin_s) + (size_t)lyr * 65536;
  const float* bpost = (ch ? bpost_d : bpost_s) + lyr * 256;
  const float* blin = (ch ? blin_d : blin_s) + lyr * 256;
  int t = threadIdx.x;
  bp[t] = bpost[t];
  __syncthreads();
  float s = blin[t];
  for (int k = 0; k < 256; ++k) s = fmaf(Wlin[t * 256 + k], bp[k], s);
  bfv4[z * 256 + t] = s;
}

__global__ __launch_bounds__(256) void k_wout(const u16* __restrict__ x,
                                              const float* __restrict__ w,
                                              const float* __restrict__ b,
                                              float* __restrict__ out, int N) {
  int wid = threadIdx.x >> 6, lane = threadIdx.x & 63;
  int n = blockIdx.x * 4 + wid;
  if (n >= N) return;
  ushort4 xv = *(const ushort4*)(x + (size_t)n * 256 + lane * 4);
  const float4 wv = *(const float4*)(w + lane * 4);
  float s = (float)__builtin_bit_cast(_Float16, xv.x) * wv.x +
            (float)__builtin_bit_cast(_Float16, xv.y) * wv.y +
            (float)__builtin_bit_cast(_Float16, xv.z) * wv.z +
            (float)__builtin_bit_cast(_Float16, xv.w) * wv.w;
#pragma unroll
  for (int off = 32; off > 0; off >>= 1) s += __shfl_down(s, off);
  if (lane == 0) out[n] = s + b[0];
}

extern "C" void kernel_launch(void* const* d_in, const int* in_sizes, int n_in,
                              void* d_out, int out_size, void* d_ws, size_t ws_size,
                              hipStream_t stream) {
  const float* x0      = (const float*)d_in[0];
  const int*   ei_in   = (const int*)d_in[1];
  const int*   ei_out  = (const int*)d_in[2];
  const float* Wpre_s  = (const float*)d_in[3];
  const float* bpre_s  = (const float*)d_in[4];
  const float* Wpost_s = (const float*)d_in[5];
  const float* bpost_s = (const float*)d_in[6];
  const float* Wlin_s  = (const float*)d_in[7];
  const float* blin_s  = (const float*)d_in[8];
  const float* Wpre_d  = (const float*)d_in[9];
  const float* bpre_d  = (const float*)d_in[10];
  const float* Wpost_d = (const float*)d_in[11];
  const float* bpost_d = (const float*)d_in[12];
  const float* Wlin_d  = (const float*)d_in[13];
  const float* blin_d  = (const float*)d_in[14];
  const float* Wcomb   = (const float*)d_in[15];
  const float* bcomb   = (const float*)d_in[16];
  const float* Wout    = (const float*)d_in[17];
  const float* bout    = (const float*)d_in[18];
  float* out = (float*)d_out;

  char* p = (char*)d_ws;
  auto alloc = [&](size_t b) {
    char* r = p;
    p += (b + 255) & ~(size_t)255;
    return r;
  };
  int* deg2     = (int*)alloc((size_t)2 * NN * 4);
  int* cur2     = (int*)alloc((size_t)2 * NN * 4);
  int* rp2      = (int*)alloc((size_t)(2 * NN + 1) * 4);
  int* col2     = (int*)alloc((size_t)2 * NE * 4);
  u16* AB2      = (u16*)alloc((size_t)2 * NN * 512 * 2);
  u16* agg52    = (u16*)alloc((size_t)2 * NN * 1280 * 2);
  float* scal32 = (float*)alloc((size_t)2 * NN * 4 * 4);
  u16* xcat1    = (u16*)alloc((size_t)NN * 768 * 2);
  u16* xcat2    = (u16*)alloc((size_t)NN * 768 * 2);
  u16* pre2     = (u16*)alloc((size_t)4 * 256 * 512 * 2);
  u16* lincat   = (u16*)alloc((size_t)4 * 256 * 256 * 2);
  u16* combB    = (u16*)alloc((size_t)2 * 256 * 768 * 2);
  u16* Wf4      = (u16*)alloc((size_t)4 * 256 * 4096 * 2);
  float* bfv4   = (float*)alloc((size_t)4 * 256 * 4);
  float* bpre4  = (float*)alloc((size_t)4 * 256 * 4);
  u16* WpostT4  = (u16*)agg52;  // alias: consumed upfront, before agg52 is written
  u16* xfin     = xcat1;        // alias: xcat1 dead after layer-1 comb

  const int BIG = 1 << 30;

  k_cvtw<<<1152, 256, 0, stream>>>(Wpre_s, Wpre_d, Wlin_s, Wlin_d, Wcomb,
                                   pre2, lincat, combB);
  k_cvtx<<<5000, 256, 0, stream>>>(x0, xcat1, bpre_s, bpre_d, bpre4);
  hipMemsetAsync(deg2, 0, (size_t)4 * NN * 4, stream);  // deg2 + cur2 (contiguous)
  k_count2<<<dim3(1250, 2), 256, 0, stream>>>(ei_in, ei_out, deg2, NE);
  k_scan<<<1, 1024, 0, stream>>>(deg2, rp2, 2 * NN);
  k_scatter2<<<dim3(1250, 2), 256, 0, stream>>>(ei_in, ei_out, rp2, cur2, col2, NE);
  k_tc4<<<dim3(128, 8, 4), 256, 0, stream>>>(Wpost_s, Wpost_d, WpostT4);
  k_mgemm<<<dim3(16, 4, 4), 512, 0, stream>>>(
      lincat, 256, WpostT4, WpostT4, 256, BIG, nullptr, 0,
      Wf4, 4096, 256, 256, 0, 65536, 1048576, 1048576);
  k_bfuse4<<<4, 256, 0, stream>>>(Wlin_s, Wlin_d, bpost_s, bpost_d, blin_s, blin_d, bfv4);

  u16* xcs[2] = {xcat1, xcat2};
  for (int lyr = 0; lyr < 2; ++lyr) {
    u16* xc = xcs[lyr];
    // [A | B] = x @ [W1 | W2]^T for both channels (z) -> AB2 fp16 [2][NN][512]
    k_mgemm<<<dim3(2, 313, 2), 512, 0, stream>>>(
        xc, 768, pre2 + (size_t)lyr * 2 * 131072, pre2 + (size_t)lyr * 2 * 131072 + 256,
        512, 256, bpre4 + (size_t)lyr * 2 * 256, 256,
        AB2, 512, NN, 256, 0, 0, 131072, NN * 512);
    k_aggregate<<<dim3(5000, 2), 256, 0, stream>>>(AB2, rp2, col2, agg52, scal32);
    // h_{s,d} = relu(V @ Wf^T + bf) -> xc cols [256:512) and [512:768)
    k_pgemm<<<320, 512, 0, stream>>>(
        xc, agg52, scal32, Wf4 + (size_t)lyr * 2 * 1048576, bfv4 + lyr * 512, xc, NN);
    // x_next = relu([x, h_in, h_out] @ Wcomb^T + bcomb)
    if (lyr == 0) {
      k_mgemm<<<dim3(1, 313, 1), 512, 0, stream>>>(
          xc, 768, combB, combB, 768, BIG, bcomb, 0,
          xcat2, 768, NN, 768, 1, 0, 0, 0);
    } else {
      k_mgemm<<<dim3(1, 313, 1), 512, 0, stream>>>(
          xc, 768, combB + 196608, combB + 196608, 768, BIG, bcomb + 256, 0,
          xfin, 256, NN, 768, 1, 0, 0, 0);
    }
  }
  k_wout<<<5000, 256, 0, stream>>>(xfin, Wout, bout, out, NN);
}